// Round 11
// baseline (2541.284 us; speedup 1.0000x reference)
//
#include <hip/hip_runtime.h>
#include <float.h>

#define Bz   4
#define Cz   128
#define Nz   8192
#define Kz   20
#define OUTz 128

typedef float f16v __attribute__((ext_vector_type(16)));

// ---------------------------------------------------------------------------
// Kernel 1: xx[b*N+n] = sum_c x[b][c][n]^2   (unchanged)
// ---------------------------------------------------------------------------
__global__ __launch_bounds__(256) void xx_kernel(const float* __restrict__ x,
                                                 float* __restrict__ xx) {
    int t = blockIdx.x * 256 + threadIdx.x;          // 0 .. B*N-1
    int b = t >> 13;
    int n = t & (Nz - 1);
    const float* xp = x + (size_t)b * Cz * Nz + n;
    float s = 0.f;
#pragma unroll 8
    for (int c = 0; c < Cz; ++c) {
        float v = xp[(size_t)c * Nz];
        s = fmaf(v, v, s);
    }
    xx[t] = s;
}

// ---------------------------------------------------------------------------
// Kernel 2: pairwise-score GEMM + per-row top-20; SGPR-A / global-B, LDS-free
// barrier-free inner loop, 4 keys per thread.
// Grid (N/32, B) = 1024 blocks, block 256. Block = 32 queries (wave-uniform
// -> A via inline-asm s_load_dwordx16 pairs into SGPRs, double-buffered).
// R10 lesson: lgkmcnt(0) waits ALL outstanding SMEM, so the effective A
// pipeline depth is ONE c-step regardless of buffering; the fix is more FMAs
// per step: 4 keys/thread -> 128 FMAs (256 cyc) cover per wait, 4x fewer
// waits, 4x less SMEM traffic.
// B: thread owns keys 4*tid..+3 of each 1024-key pass; one coalesced float4
// load per c-step, 4-buffer rotation loading c+2 (512-cycle cover, L2-hit).
// Selection per pass: 16 sub-phases of 64 keys; writers tids [16sp,16sp+16)
// dump their 4 cols x 32 rows into the rotated 8KB sc tile; scan/extract
// IDENTICAL to rounds 7-10 (ascending pass -> sub-phase -> j, strict >,
// stale-superset mask + live-wv recheck).
// Per-pair fp32 chain (ascending c, single fmaf(A,B,acc), 2*acc-xx)
// IDENTICAL to rounds 1-10 -> bit-identical output.
// ---------------------------------------------------------------------------
__global__ __launch_bounds__(256) void knn_kernel(const float* __restrict__ x,
                                                  const float* __restrict__ xxg,
                                                  int* __restrict__ idxout) {
    const int b  = blockIdx.y;
    const int q0 = blockIdx.x * 32;

    __shared__ float sc[32 * 64];   // 8KB score tile (selection only)

    const int tid  = threadIdx.x;
    const int lane = tid & 63;
    const int wid  = tid >> 6;

    const float* xb = x + (size_t)b * Cz * Nz;
    const float* aq = xb + q0;      // A base: row c at aq + (c<<13) (uniform)

    // top-20 state: owners = lanes 0..7 of each wave; row orow = wid*8+lane
    float tv[Kz];
    int   ti[Kz];
#pragma unroll
    for (int s = 0; s < Kz; ++s) { tv[s] = -FLT_MAX; ti[s] = 0; }
    float wv = -FLT_MAX;
    int wslot = 0;
    const int orow = wid * 8 + lane;           // owner row (lane<8)
    const int srow = wid * 8 + (lane & 7);     // scanned row (all lanes)
    const int part = lane >> 3;                // 8-col part (0..7)

    // SGPR A double buffer (2 x 32 floats)
    f16v sA0, sB0, sA1, sB1;
    // prologue: c=0 into set0 (each pass's last CSTEP re-issues c=0 wrapped)
    asm volatile("s_load_dwordx16 %0, %2, 0x0\n\t"
                 "s_load_dwordx16 %1, %2, 0x40"
                 : "=&s"(sA0), "=&s"(sB0) : "s"(aq));

// one c-step: issue B load for c+2, wait current A set (covers the set
// issued one step = 128 FMAs ago), issue A set for c+1, 128 FMAs.
#define CSTEP(cA, cB, nA, nB, vbc, vbn, cidx)                                 \
    {                                                                         \
        const int cb_ = ((cidx) + 2) & 127;                                   \
        vbn = *(const float4*)&bp[(size_t)cb_ * Nz];                          \
        const int cn_ = ((cidx) + 1) & 127;                                   \
        const float* apn_ = aq + ((size_t)cn_ << 13);                         \
        asm volatile("s_waitcnt lgkmcnt(0)" : "+s"(cA), "+s"(cB));            \
        asm volatile("s_load_dwordx16 %0, %2, 0x0\n\t"                        \
                     "s_load_dwordx16 %1, %2, 0x40"                           \
                     : "=&s"(nA), "=&s"(nB) : "s"(apn_));                     \
        const float4 vv_ = (vbc);                                             \
        _Pragma("unroll")                                                     \
        for (int q = 0; q < 16; ++q) {                                        \
            acc[4 * q + 0] = fmaf(cA[q], vv_.x, acc[4 * q + 0]);              \
            acc[4 * q + 1] = fmaf(cA[q], vv_.y, acc[4 * q + 1]);              \
            acc[4 * q + 2] = fmaf(cA[q], vv_.z, acc[4 * q + 2]);              \
            acc[4 * q + 3] = fmaf(cA[q], vv_.w, acc[4 * q + 3]);              \
        }                                                                     \
        _Pragma("unroll")                                                     \
        for (int q = 0; q < 16; ++q) {                                        \
            acc[64 + 4 * q + 0] = fmaf(cB[q], vv_.x, acc[64 + 4 * q + 0]);    \
            acc[64 + 4 * q + 1] = fmaf(cB[q], vv_.y, acc[64 + 4 * q + 1]);    \
            acc[64 + 4 * q + 2] = fmaf(cB[q], vv_.z, acc[64 + 4 * q + 2]);    \
            acc[64 + 4 * q + 3] = fmaf(cB[q], vv_.w, acc[64 + 4 * q + 3]);    \
        }                                                                     \
    }

#define EXTRACT(pm_, gbase_)                                                  \
    {                                                                         \
        unsigned long long pm = (pm_);                                        \
        while (pm) {                                                          \
            int j = __ffsll(pm) - 1;                                          \
            pm &= pm - 1;                                                     \
            float s = sc[orow * 64 + ((j + 4 * orow) & 63)];                  \
            if (s > wv) {                                                     \
                int gj = (gbase_) + j;                                        \
                _Pragma("unroll")                                             \
                for (int s2 = 0; s2 < Kz; ++s2) {                             \
                    bool hit = (s2 == wslot);                                 \
                    tv[s2] = hit ? s : tv[s2];                                \
                    ti[s2] = hit ? gj : ti[s2];                               \
                }                                                             \
                wv = tv[0]; wslot = 0;                                        \
                _Pragma("unroll")                                             \
                for (int s2 = 1; s2 < Kz; ++s2)                               \
                    if (tv[s2] < wv) { wv = tv[s2]; wslot = s2; }             \
            }                                                                 \
        }                                                                     \
    }

#pragma unroll 1
    for (int kp = 0; kp < Nz / 1024; ++kp) {
        const float* bp = xb + kp * 1024 + 4 * tid;   // thread's 4 keys

        float acc[128];
#pragma unroll
        for (int q = 0; q < 128; ++q) acc[q] = 0.f;

        // B prologue: c=0 and c=1 (overwrites last pass's stale prefetch)
        float4 vb0, vb1, vb2, vb3;
        vb0 = *(const float4*)&bp[0];
        vb1 = *(const float4*)&bp[(size_t)Nz];

#pragma unroll 1
        for (int c4 = 0; c4 < 32; ++c4) {       // 4 c-steps per iteration
            const int c = 4 * c4;
            CSTEP(sA0, sB0, sA1, sB1, vb0, vb2, c + 0)
            CSTEP(sA1, sB1, sA0, sB0, vb1, vb3, c + 1)
            CSTEP(sA0, sB0, sA1, sB1, vb2, vb0, c + 2)
            CSTEP(sA1, sB1, sA0, sB0, vb3, vb1, c + 3)
        }

        // ---- selection: 16 sub-phases of 64 keys over the 8KB sc tile ----
        const float4 xxk =
            *(const float4*)&xxg[b * Nz + kp * 1024 + 4 * tid];
#pragma unroll 1
        for (int sp = 0; sp < 16; ++sp) {
            if ((tid >> 4) == sp) {
                const int cl = (tid & 15) * 4;
#pragma unroll
                for (int q = 0; q < 32; ++q) {
                    float4 w;
                    w.x = 2.f * acc[4 * q + 0] - xxk.x;
                    w.y = 2.f * acc[4 * q + 1] - xxk.y;
                    w.z = 2.f * acc[4 * q + 2] - xxk.z;
                    w.w = 2.f * acc[4 * q + 3] - xxk.w;
                    *(float4*)&sc[q * 64 + ((cl + 4 * q) & 63)] = w;
                }
            }
            __syncthreads();

            float wvb = __shfl(wv, lane & 7);
            unsigned m = 0;
#pragma unroll
            for (int g = 0; g < 2; ++g) {
                int col = part * 8 + g * 4;
                float4 v = *(const float4*)&sc[srow * 64 + ((col + 4 * srow) & 63)];
                m |= (unsigned)(v.x > wvb) << (4 * g + 0);
                m |= (unsigned)(v.y > wvb) << (4 * g + 1);
                m |= (unsigned)(v.z > wvb) << (4 * g + 2);
                m |= (unsigned)(v.w > wvb) << (4 * g + 3);
            }
            unsigned long long f = (unsigned long long)m << (8 * part);
            f |= __shfl_xor(f, 8);
            f |= __shfl_xor(f, 16);
            f |= __shfl_xor(f, 32);
            if (lane < 8) { EXTRACT(f, kp * 1024 + sp * 64); }
            __syncthreads();
        }
    }

    if (lane < 8) {
        size_t base = ((size_t)b * Nz + q0 + orow) * Kz;
#pragma unroll
        for (int s = 0; s < Kz; ++s) idxout[base + s] = ti[s];
    }
#undef CSTEP
#undef EXTRACT
}

// ---------------------------------------------------------------------------
// Kernel 3: Y[p][o'] (unchanged)
// ---------------------------------------------------------------------------
__global__ __launch_bounds__(256) void feat_kernel(const float* __restrict__ x,
                                                   const float* __restrict__ W,
                                                   const float* __restrict__ bias,
                                                   float* __restrict__ Y) {
    const int gp0 = blockIdx.x * 64;         // global point index (b*N+n)
    const int b   = gp0 >> 13;
    const int n0  = gp0 & (Nz - 1);
    const int o0  = blockIdx.y * 64;

    __shared__ __align__(16) float xt[128 * 64];   // [c][p]
    __shared__ __align__(16) float wt[128 * 64];   // [c][o']

    const int tid = threadIdx.x;
    const int tx  = tid & 15;
    const int ty  = tid >> 4;

    {
        int li = tid & 63;
        int c0 = tid >> 6;
        const float* xbp = x + (size_t)b * Cz * Nz + n0;
#pragma unroll
        for (int rep = 0; rep < 32; ++rep) {
            int c = c0 + rep * 4;
            xt[c * 64 + li] = xbp[(size_t)c * Nz + li];
        }
    }
    {
        int lo = tid & 63;
        int c0 = tid >> 6;
        int oo = o0 + lo;
#pragma unroll
        for (int rep = 0; rep < 32; ++rep) {
            int c = c0 + rep * 4;
            float w;
            if (oo < 128) w = W[oo * 256 + c] + W[oo * 256 + 128 + c];
            else          w = W[(oo - 128) * 256 + 128 + c];
            wt[c * 64 + lo] = w;
        }
    }
    __syncthreads();

    float acc[4][4];
#pragma unroll
    for (int di = 0; di < 4; ++di)
#pragma unroll
        for (int dj = 0; dj < 4; ++dj) acc[di][dj] = 0.f;

    const int aoff = ty * 4;
    const int boff = tx * 4;
#pragma unroll 8
    for (int c = 0; c < 128; ++c) {
        float4 a  = *(const float4*)&xt[c * 64 + aoff];
        float4 ww = *(const float4*)&wt[c * 64 + boff];
        float av[4] = {a.x, a.y, a.z, a.w};
        float wvv[4] = {ww.x, ww.y, ww.z, ww.w};
#pragma unroll
        for (int di = 0; di < 4; ++di)
#pragma unroll
            for (int dj = 0; dj < 4; ++dj)
                acc[di][dj] = fmaf(av[di], wvv[dj], acc[di][dj]);
    }

    float4 bv = make_float4(0.f, 0.f, 0.f, 0.f);
    if (o0 < 128) bv = *(const float4*)&bias[o0 + tx * 4];
#pragma unroll
    for (int di = 0; di < 4; ++di) {
        float4 r;
        r.x = acc[di][0] + bv.x;
        r.y = acc[di][1] + bv.y;
        r.z = acc[di][2] + bv.z;
        r.w = acc[di][3] + bv.w;
        *(float4*)&Y[(size_t)(gp0 + ty * 4 + di) * 256 + o0 + tx * 4] = r;
    }
}

// ---------------------------------------------------------------------------
// Kernel 4: out[b][o][n] = relu(u[n][o] - min_j v[idx[n][j]][o])  (unchanged)
// ---------------------------------------------------------------------------
__global__ __launch_bounds__(256) void gather_kernel(const int* __restrict__ idxg,
                                                     const float* __restrict__ Y,
                                                     float* __restrict__ out) {
    const int gp0 = blockIdx.x * 64;
    const int b   = gp0 >> 13;
    const int n0  = gp0 & (Nz - 1);

    __shared__ int lidx[64 * 21];
    const int tid = threadIdx.x;
    for (int t = tid; t < 64 * Kz; t += 256) {
        int p = t / Kz, j = t - p * Kz;
        lidx[p * 21 + j] = idxg[(size_t)(gp0 + p) * Kz + j];
    }
    __syncthreads();

    const int p  = tid & 63;
    const int o0 = (tid >> 6) * 32;

    float mn[32];
#pragma unroll
    for (int q = 0; q < 32; ++q) mn[q] = FLT_MAX;

    for (int j = 0; j < Kz; ++j) {
        int m = lidx[p * 21 + j];
        const float4* vr =
            (const float4*)(Y + (size_t)(b * Nz + m) * 256 + 128 + o0);
#pragma unroll
        for (int q = 0; q < 8; ++q) {
            float4 v4 = vr[q];
            mn[4 * q + 0] = fminf(mn[4 * q + 0], v4.x);
            mn[4 * q + 1] = fminf(mn[4 * q + 1], v4.y);
            mn[4 * q + 2] = fminf(mn[4 * q + 2], v4.z);
            mn[4 * q + 3] = fminf(mn[4 * q + 3], v4.w);
        }
    }

    const float4* ur = (const float4*)(Y + (size_t)(gp0 + p) * 256 + o0);
#pragma unroll
    for (int q = 0; q < 8; ++q) {
        float4 u4 = ur[q];
        float r0 = fmaxf(u4.x - mn[4 * q + 0], 0.f);
        float r1 = fmaxf(u4.y - mn[4 * q + 1], 0.f);
        float r2 = fmaxf(u4.z - mn[4 * q + 2], 0.f);
        float r3 = fmaxf(u4.w - mn[4 * q + 3], 0.f);
        size_t ob = ((size_t)b * OUTz + o0 + 4 * q) * Nz + n0 + p;
        out[ob + 0 * Nz] = r0;
        out[ob + 1 * Nz] = r1;
        out[ob + 2 * Nz] = r2;
        out[ob + 3 * Nz] = r3;
    }
}

// ---------------------------------------------------------------------------
extern "C" void kernel_launch(void* const* d_in, const int* in_sizes, int n_in,
                              void* d_out, int out_size, void* d_ws, size_t ws_size,
                              hipStream_t stream) {
    const float* x    = (const float*)d_in[0];
    const float* W    = (const float*)d_in[1];
    const float* bias = (const float*)d_in[2];
    float* out = (float*)d_out;

    char* ws = (char*)d_ws;
    float* xx  = (float*)ws;                       // 128KB  @ 0
    int*   idx = (int*)(ws + (1 << 17));           // 2.62MB @ 128KB
    float* Y   = (float*)(ws + (4 << 20));         // 32MB   @ 4MB

    xx_kernel<<<dim3(Bz * Nz / 256), dim3(256), 0, stream>>>(x, xx);

    knn_kernel<<<dim3(Nz / 32, Bz), dim3(256), 0, stream>>>(x, xx, idx);

    feat_kernel<<<dim3(Bz * Nz / 64, 4), dim3(256), 0, stream>>>(x, W, bias, Y);

    gather_kernel<<<dim3(Bz * Nz / 64), dim3(256), 0, stream>>>(idx, Y, out);
}

// Round 12
// 2260.353 us; speedup vs baseline: 1.1243x; 1.1243x over previous
//
#include <hip/hip_runtime.h>
#include <float.h>

#define Bz   4
#define Cz   128
#define Nz   8192
#define Kz   20
#define OUTz 128

// ---------------------------------------------------------------------------
// Kernel 1: xx[b*N+n] = sum_c x[b][c][n]^2   (unchanged)
// ---------------------------------------------------------------------------
__global__ __launch_bounds__(256) void xx_kernel(const float* __restrict__ x,
                                                 float* __restrict__ xx) {
    int t = blockIdx.x * 256 + threadIdx.x;          // 0 .. B*N-1
    int b = t >> 13;
    int n = t & (Nz - 1);
    const float* xp = x + (size_t)b * Cz * Nz + n;
    float s = 0.f;
#pragma unroll 8
    for (int c = 0; c < Cz; ++c) {
        float v = xp[(size_t)c * Nz];
        s = fmaf(v, v, s);
    }
    xx[t] = s;
}

// ---------------------------------------------------------------------------
// Kernel 2: pairwise-score GEMM + per-row top-20.
// Grid (N/64, B) = 512 blocks, block 256. Block = 64 queries x 256-key pass.
// Thread (wid=tid>>6, lane=tid&63): queries [16*wid,16*wid+16), keys
// [4*lane, 4*lane+4) of the pass.
// KEY IDEA (R12): LDS holds ONLY A (Ald 64q x 128c, 32KB, staged once).
// Per c-step the A read is wave-uniform (all 64 lanes same address) ->
// LDS broadcast, conflict-free, 16B/instr on the LDS pipe. B streams
// directly global->register: one coalesced float4 per c-step (wave = 1KB
// contiguous), 4-slot rotation prefetching c+4 (~500-cyc cover), x[b] =
// 4MB = one XCD L2. Inner loop: no barriers, no LDS writes, 64 FMA/step.
// R7's audit showed LDS-B-staging pinned VALUBusy at ~55% (LDS pipe parity);
// this removes the per-lane LDS traffic entirely. No inline asm (R10/R11:
// SGPR path dead - occupancy/codegen collapse).
// Selection: R7/R8's proven 4 x 64-col rotated sc tile (standalone 16KB),
// writers (lane>>4)==h, scan part=lane>>4, owners lane<16, ascending
// pass -> sub-phase -> j, strict >, stale-superset mask + live-wv recheck.
// Per-pair fp32 chain (ascending c, single fmaf(A,B,acc), 2*acc-xx)
// IDENTICAL to rounds 1-11 -> bit-identical output.
// ---------------------------------------------------------------------------
__global__ __launch_bounds__(256) void knn_kernel(const float* __restrict__ x,
                                                  const float* __restrict__ xxg,
                                                  int* __restrict__ idxout) {
    const int b  = blockIdx.y;
    const int q0 = blockIdx.x * 64;

    __shared__ __align__(16) float Ald[128 * 64];   // 32KB [c][q]
    __shared__ __align__(16) float sc[64 * 64];     // 16KB [q][col rot]

    const int tid  = threadIdx.x;
    const int lane = tid & 63;
    const int wid  = tid >> 6;

    const float* xb = x + (size_t)b * Cz * Nz;

    // stage A once: Ald[c][q] = x[b][c][q0+q]
    {
        int q4 = (tid & 15) * 4;
        int c0 = tid >> 4;          // 0..15
#pragma unroll
        for (int rep = 0; rep < 8; ++rep) {
            int c = c0 + rep * 16;
            *(float4*)&Ald[c * 64 + q4] =
                *(const float4*)&xb[(size_t)c * Nz + q0 + q4];
        }
    }
    __syncthreads();

    // top-20 state: owners = lanes 0..15 of each wave, row orow
    float tv[Kz];
    int   ti[Kz];
#pragma unroll
    for (int s = 0; s < Kz; ++s) { tv[s] = -FLT_MAX; ti[s] = 0; }
    float wv = -FLT_MAX;
    int wslot = 0;
    const int orow = wid * 16 + lane;            // owner row (lane<16)
    const int srow = wid * 16 + (lane & 15);     // scanned row (all lanes)
    const int part = lane >> 4;                  // 16-col part (0..3)
    const int aoff = wid * 16;                   // this wave's query base

// one c-step: read A fragment (broadcast), rotate B buffer (use cur, issue
// load for c+4 into the freed slot), 64 FMAs.
#define CSTEP(vb, cc)                                                         \
    {                                                                         \
        const float4 cur_ = vb;                                               \
        vb = *(const float4*)&bp[(size_t)(((cc) + 4) & 127) * Nz];            \
        const float* ar_ = &Ald[(cc) * 64 + aoff];                            \
        float4 a0_ = *(const float4*)(ar_);                                   \
        float4 a1_ = *(const float4*)(ar_ + 4);                               \
        float4 a2_ = *(const float4*)(ar_ + 8);                               \
        float4 a3_ = *(const float4*)(ar_ + 12);                              \
        float av_[16] = {a0_.x, a0_.y, a0_.z, a0_.w,                          \
                         a1_.x, a1_.y, a1_.z, a1_.w,                          \
                         a2_.x, a2_.y, a2_.z, a2_.w,                          \
                         a3_.x, a3_.y, a3_.z, a3_.w};                         \
        _Pragma("unroll")                                                     \
        for (int q = 0; q < 16; ++q) {                                        \
            acc[q][0] = fmaf(av_[q], cur_.x, acc[q][0]);                      \
            acc[q][1] = fmaf(av_[q], cur_.y, acc[q][1]);                      \
            acc[q][2] = fmaf(av_[q], cur_.z, acc[q][2]);                      \
            acc[q][3] = fmaf(av_[q], cur_.w, acc[q][3]);                      \
        }                                                                     \
    }

#define EXTRACT(pm_, gbase_)                                                  \
    {                                                                         \
        unsigned long long pm = (pm_);                                        \
        while (pm) {                                                          \
            int j = __ffsll(pm) - 1;                                          \
            pm &= pm - 1;                                                     \
            float s = sc[orow * 64 + ((j + 4 * orow) & 63)];                  \
            if (s > wv) {                                                     \
                int gj = (gbase_) + j;                                        \
                _Pragma("unroll")                                             \
                for (int s2 = 0; s2 < Kz; ++s2) {                             \
                    bool hit = (s2 == wslot);                                 \
                    tv[s2] = hit ? s : tv[s2];                                \
                    ti[s2] = hit ? gj : ti[s2];                               \
                }                                                             \
                wv = tv[0]; wslot = 0;                                        \
                _Pragma("unroll")                                             \
                for (int s2 = 1; s2 < Kz; ++s2)                               \
                    if (tv[s2] < wv) { wv = tv[s2]; wslot = s2; }             \
            }                                                                 \
        }                                                                     \
    }

#pragma unroll 1
    for (int kp = 0; kp < Nz / 256; ++kp) {
        const float* bp = xb + kp * 256 + 4 * lane;   // thread's 4 keys

        float acc[16][4];
#pragma unroll
        for (int q = 0; q < 16; ++q)
#pragma unroll
            for (int i = 0; i < 4; ++i) acc[q][i] = 0.f;

        // B prologue: c = 0..3
        float4 vb0 = *(const float4*)&bp[0];
        float4 vb1 = *(const float4*)&bp[(size_t)1 * Nz];
        float4 vb2 = *(const float4*)&bp[(size_t)2 * Nz];
        float4 vb3 = *(const float4*)&bp[(size_t)3 * Nz];

#pragma unroll 1
        for (int c4 = 0; c4 < 16; ++c4) {       // 8 c-steps per iteration
            const int c = 8 * c4;
            CSTEP(vb0, c + 0)
            CSTEP(vb1, c + 1)
            CSTEP(vb2, c + 2)
            CSTEP(vb3, c + 3)
            CSTEP(vb0, c + 4)
            CSTEP(vb1, c + 5)
            CSTEP(vb2, c + 6)
            CSTEP(vb3, c + 7)
        }

        // ---- selection: four 64-col sub-phases over the sc tile ----
        const float4 xxk = *(const float4*)&xxg[b * Nz + kp * 256 + 4 * lane];
#pragma unroll
        for (int h = 0; h < 4; ++h) {
            // sub-phase h = global cols [kp*256 + h*64, +64): lanes 16h..16h+15
            if ((lane >> 4) == h) {
                const int cl = (lane & 15) * 4;
#pragma unroll
                for (int dq = 0; dq < 16; ++dq) {
                    int r = wid * 16 + dq;
                    float4 w;
                    w.x = 2.f * acc[dq][0] - xxk.x;
                    w.y = 2.f * acc[dq][1] - xxk.y;
                    w.z = 2.f * acc[dq][2] - xxk.z;
                    w.w = 2.f * acc[dq][3] - xxk.w;
                    *(float4*)&sc[r * 64 + ((cl + 4 * r) & 63)] = w;
                }
            }
            __syncthreads();

            // scan: lane (srow, part) covers 16 cols
            float wvb = __shfl(wv, lane & 15);
            unsigned m = 0;
#pragma unroll
            for (int g = 0; g < 4; ++g) {
                int col = part * 16 + g * 4;
                float4 v = *(const float4*)&sc[srow * 64 + ((col + 4 * srow) & 63)];
                m |= (unsigned)(v.x > wvb) << (4 * g + 0);
                m |= (unsigned)(v.y > wvb) << (4 * g + 1);
                m |= (unsigned)(v.z > wvb) << (4 * g + 2);
                m |= (unsigned)(v.w > wvb) << (4 * g + 3);
            }
            unsigned long long f = (unsigned long long)m << (16 * part);
            f |= __shfl_xor(f, 16);
            f |= __shfl_xor(f, 32);
            if (lane < 16) { EXTRACT(f, kp * 256 + h * 64); }
            __syncthreads();   // extraction done before next write (phase/pass)
        }
    }

    if (lane < 16) {
        size_t base = ((size_t)b * Nz + q0 + orow) * Kz;
#pragma unroll
        for (int s = 0; s < Kz; ++s) idxout[base + s] = ti[s];
    }
#undef CSTEP
#undef EXTRACT
}

// ---------------------------------------------------------------------------
// Kernel 3: Y[p][o'] (unchanged)
// ---------------------------------------------------------------------------
__global__ __launch_bounds__(256) void feat_kernel(const float* __restrict__ x,
                                                   const float* __restrict__ W,
                                                   const float* __restrict__ bias,
                                                   float* __restrict__ Y) {
    const int gp0 = blockIdx.x * 64;         // global point index (b*N+n)
    const int b   = gp0 >> 13;
    const int n0  = gp0 & (Nz - 1);
    const int o0  = blockIdx.y * 64;

    __shared__ __align__(16) float xt[128 * 64];   // [c][p]
    __shared__ __align__(16) float wt[128 * 64];   // [c][o']

    const int tid = threadIdx.x;
    const int tx  = tid & 15;
    const int ty  = tid >> 4;

    {
        int li = tid & 63;
        int c0 = tid >> 6;
        const float* xbp = x + (size_t)b * Cz * Nz + n0;
#pragma unroll
        for (int rep = 0; rep < 32; ++rep) {
            int c = c0 + rep * 4;
            xt[c * 64 + li] = xbp[(size_t)c * Nz + li];
        }
    }
    {
        int lo = tid & 63;
        int c0 = tid >> 6;
        int oo = o0 + lo;
#pragma unroll
        for (int rep = 0; rep < 32; ++rep) {
            int c = c0 + rep * 4;
            float w;
            if (oo < 128) w = W[oo * 256 + c] + W[oo * 256 + 128 + c];
            else          w = W[(oo - 128) * 256 + 128 + c];
            wt[c * 64 + lo] = w;
        }
    }
    __syncthreads();

    float acc[4][4];
#pragma unroll
    for (int di = 0; di < 4; ++di)
#pragma unroll
        for (int dj = 0; dj < 4; ++dj) acc[di][dj] = 0.f;

    const int aoff = ty * 4;
    const int boff = tx * 4;
#pragma unroll 8
    for (int c = 0; c < 128; ++c) {
        float4 a  = *(const float4*)&xt[c * 64 + aoff];
        float4 ww = *(const float4*)&wt[c * 64 + boff];
        float av[4] = {a.x, a.y, a.z, a.w};
        float wvv[4] = {ww.x, ww.y, ww.z, ww.w};
#pragma unroll
        for (int di = 0; di < 4; ++di)
#pragma unroll
            for (int dj = 0; dj < 4; ++dj)
                acc[di][dj] = fmaf(av[di], wvv[dj], acc[di][dj]);
    }

    float4 bv = make_float4(0.f, 0.f, 0.f, 0.f);
    if (o0 < 128) bv = *(const float4*)&bias[o0 + tx * 4];
#pragma unroll
    for (int di = 0; di < 4; ++di) {
        float4 r;
        r.x = acc[di][0] + bv.x;
        r.y = acc[di][1] + bv.y;
        r.z = acc[di][2] + bv.z;
        r.w = acc[di][3] + bv.w;
        *(float4*)&Y[(size_t)(gp0 + ty * 4 + di) * 256 + o0 + tx * 4] = r;
    }
}

// ---------------------------------------------------------------------------
// Kernel 4: out[b][o][n] = relu(u[n][o] - min_j v[idx[n][j]][o])  (unchanged)
// ---------------------------------------------------------------------------
__global__ __launch_bounds__(256) void gather_kernel(const int* __restrict__ idxg,
                                                     const float* __restrict__ Y,
                                                     float* __restrict__ out) {
    const int gp0 = blockIdx.x * 64;
    const int b   = gp0 >> 13;
    const int n0  = gp0 & (Nz - 1);

    __shared__ int lidx[64 * 21];
    const int tid = threadIdx.x;
    for (int t = tid; t < 64 * Kz; t += 256) {
        int p = t / Kz, j = t - p * Kz;
        lidx[p * 21 + j] = idxg[(size_t)(gp0 + p) * Kz + j];
    }
    __syncthreads();

    const int p  = tid & 63;
    const int o0 = (tid >> 6) * 32;

    float mn[32];
#pragma unroll
    for (int q = 0; q < 32; ++q) mn[q] = FLT_MAX;

    for (int j = 0; j < Kz; ++j) {
        int m = lidx[p * 21 + j];
        const float4* vr =
            (const float4*)(Y + (size_t)(b * Nz + m) * 256 + 128 + o0);
#pragma unroll
        for (int q = 0; q < 8; ++q) {
            float4 v4 = vr[q];
            mn[4 * q + 0] = fminf(mn[4 * q + 0], v4.x);
            mn[4 * q + 1] = fminf(mn[4 * q + 1], v4.y);
            mn[4 * q + 2] = fminf(mn[4 * q + 2], v4.z);
            mn[4 * q + 3] = fminf(mn[4 * q + 3], v4.w);
        }
    }

    const float4* ur = (const float4*)(Y + (size_t)(gp0 + p) * 256 + o0);
#pragma unroll
    for (int q = 0; q < 8; ++q) {
        float4 u4 = ur[q];
        float r0 = fmaxf(u4.x - mn[4 * q + 0], 0.f);
        float r1 = fmaxf(u4.y - mn[4 * q + 1], 0.f);
        float r2 = fmaxf(u4.z - mn[4 * q + 2], 0.f);
        float r3 = fmaxf(u4.w - mn[4 * q + 3], 0.f);
        size_t ob = ((size_t)b * OUTz + o0 + 4 * q) * Nz + n0 + p;
        out[ob + 0 * Nz] = r0;
        out[ob + 1 * Nz] = r1;
        out[ob + 2 * Nz] = r2;
        out[ob + 3 * Nz] = r3;
    }
}

// ---------------------------------------------------------------------------
extern "C" void kernel_launch(void* const* d_in, const int* in_sizes, int n_in,
                              void* d_out, int out_size, void* d_ws, size_t ws_size,
                              hipStream_t stream) {
    const float* x    = (const float*)d_in[0];
    const float* W    = (const float*)d_in[1];
    const float* bias = (const float*)d_in[2];
    float* out = (float*)d_out;

    char* ws = (char*)d_ws;
    float* xx  = (float*)ws;                       // 128KB  @ 0
    int*   idx = (int*)(ws + (1 << 17));           // 2.62MB @ 128KB
    float* Y   = (float*)(ws + (4 << 20));         // 32MB   @ 4MB

    xx_kernel<<<dim3(Bz * Nz / 256), dim3(256), 0, stream>>>(x, xx);

    knn_kernel<<<dim3(Nz / 64, Bz), dim3(256), 0, stream>>>(x, xx, idx);

    feat_kernel<<<dim3(Bz * Nz / 64, 4), dim3(256), 0, stream>>>(x, W, bias, Y);

    gather_kernel<<<dim3(Bz * Nz / 64), dim3(256), 0, stream>>>(idx, Y, out);
}